// Round 1
// baseline (145.525 us; speedup 1.0000x reference)
//
#include <hip/hip_runtime.h>

#define WIN   11
#define PAD   5
#define BX    32
#define BY    32
#define IW    (BX + WIN - 1)   // 42
#define IH    (BY + WIN - 1)   // 42
#define IMG_H 512
#define IMG_W 512
#define NIMG  48               // 16 batch * 3 channels
#define C1v   1.0e-4f          // 0.01^2
#define C2v   9.0e-4f          // 0.03^2

// Gaussian window, computed to double precision then rounded to f32.
// Matches numpy's f32 window to ~1e-8 relative (arg rounded to f32 first,
// like np.exp on a float32 array).
__device__ __forceinline__ void make_window(float* w) {
    double v[WIN];
    double s = 0.0;
    #pragma unroll
    for (int i = 0; i < WIN; ++i) {
        float d   = (float)i - 5.0f;
        float arg = -(d * d) / 4.5f;      // 2*sigma^2 = 4.5
        v[i] = exp((double)arg);
        s += v[i];
    }
    #pragma unroll
    for (int i = 0; i < WIN; ++i) w[i] = (float)(v[i] / s);
}

__global__ __launch_bounds__(256) void ssim_tile_kernel(
        const float* __restrict__ pred,
        const float* __restrict__ targ,
        float* __restrict__ partial) {
    // raw input tiles with halo (+1 pad column vs bank aliasing)
    __shared__ float sp[IH][IW + 1];
    __shared__ float st[IH][IW + 1];
    // horizontally-filtered stats (rows still carry vertical halo)
    __shared__ float h1 [IH][BX + 1];
    __shared__ float h2 [IH][BX + 1];
    __shared__ float h11[IH][BX + 1];
    __shared__ float h22[IH][BX + 1];
    __shared__ float h12[IH][BX + 1];
    __shared__ float wavesum[4];

    float w[WIN];
    make_window(w);

    const int n  = blockIdx.z;          // image index (N*C)
    const int x0 = blockIdx.x * BX;
    const int y0 = blockIdx.y * BY;
    const int tid = threadIdx.x;
    const float* __restrict__ P = pred + (size_t)n * IMG_H * IMG_W;
    const float* __restrict__ T = targ + (size_t)n * IMG_H * IMG_W;

    // ---- stage 42x42 halo tile, zero-filled outside the image ----
    for (int idx = tid; idx < IH * IW; idx += 256) {
        const int r  = idx / IW;
        const int c  = idx - r * IW;
        const int gy = y0 - PAD + r;
        const int gx = x0 - PAD + c;
        float p = 0.0f, t = 0.0f;
        if (gy >= 0 && gy < IMG_H && gx >= 0 && gx < IMG_W) {
            const int g = gy * IMG_W + gx;
            p = P[g];
            t = T[g];
        }
        sp[r][c] = p;
        st[r][c] = t;
    }
    __syncthreads();

    // ---- horizontal 11-tap pass: products first, then filter ----
    for (int idx = tid; idx < IH * BX; idx += 256) {
        const int r = idx / BX;
        const int c = idx - r * BX;
        float s1 = 0.f, s2 = 0.f, s11 = 0.f, s22 = 0.f, s12 = 0.f;
        #pragma unroll
        for (int j = 0; j < WIN; ++j) {
            const float wj = w[j];
            const float p = sp[r][c + j];
            const float t = st[r][c + j];
            s1  += wj * p;
            s2  += wj * t;
            s11 += wj * (p * p);
            s22 += wj * (t * t);
            s12 += wj * (p * t);
        }
        h1 [r][c] = s1;
        h2 [r][c] = s2;
        h11[r][c] = s11;
        h22[r][c] = s22;
        h12[r][c] = s12;
    }
    __syncthreads();

    // ---- vertical 11-tap pass + SSIM map + local accumulate ----
    float acc = 0.0f;
    for (int idx = tid; idx < BY * BX; idx += 256) {
        const int y = idx / BX;
        const int x = idx - y * BX;
        float mu1 = 0.f, mu2 = 0.f, e11 = 0.f, e22 = 0.f, e12 = 0.f;
        #pragma unroll
        for (int j = 0; j < WIN; ++j) {
            const float wj = w[j];
            mu1 += wj * h1 [y + j][x];
            mu2 += wj * h2 [y + j][x];
            e11 += wj * h11[y + j][x];
            e22 += wj * h22[y + j][x];
            e12 += wj * h12[y + j][x];
        }
        const float mu1sq = mu1 * mu1;
        const float mu2sq = mu2 * mu2;
        const float mu12  = mu1 * mu2;
        const float s1sq  = e11 - mu1sq;
        const float s2sq  = e22 - mu2sq;
        const float s12   = e12 - mu12;
        const float num = (2.0f * mu12 + C1v) * (2.0f * s12 + C2v);
        const float den = (mu1sq + mu2sq + C1v) * (s1sq + s2sq + C2v);
        acc += num / den;
    }

    // ---- block reduction: wave shuffle tree, then cross-wave via LDS ----
    #pragma unroll
    for (int off = 32; off > 0; off >>= 1)
        acc += __shfl_down(acc, off, 64);
    const int wave = tid >> 6;
    const int lane = tid & 63;
    if (lane == 0) wavesum[wave] = acc;
    __syncthreads();
    if (tid == 0) {
        const float s = wavesum[0] + wavesum[1] + wavesum[2] + wavesum[3];
        const int bid = (blockIdx.z * gridDim.y + blockIdx.y) * gridDim.x + blockIdx.x;
        partial[bid] = s;
    }
}

__global__ __launch_bounds__(256) void ssim_reduce_kernel(
        const float* __restrict__ partial,
        float* __restrict__ out,
        int nblk, double inv_n) {
    __shared__ double wsum[4];
    double s = 0.0;
    for (int i = threadIdx.x; i < nblk; i += 256)
        s += (double)partial[i];
    #pragma unroll
    for (int off = 32; off > 0; off >>= 1)
        s += __shfl_down(s, off, 64);
    const int wave = threadIdx.x >> 6;
    if ((threadIdx.x & 63) == 0) wsum[wave] = s;
    __syncthreads();
    if (threadIdx.x == 0) {
        const double tot = wsum[0] + wsum[1] + wsum[2] + wsum[3];
        out[0] = (float)(tot * inv_n);
    }
}

extern "C" void kernel_launch(void* const* d_in, const int* in_sizes, int n_in,
                              void* d_out, int out_size, void* d_ws, size_t ws_size,
                              hipStream_t stream) {
    const float* pred = (const float*)d_in[0];
    const float* targ = (const float*)d_in[1];
    float* out     = (float*)d_out;
    float* partial = (float*)d_ws;   // 48 * 16 * 16 = 12288 floats, all written

    dim3 grid(IMG_W / BX, IMG_H / BY, NIMG);   // 16 x 16 x 48
    ssim_tile_kernel<<<grid, 256, 0, stream>>>(pred, targ, partial);

    const int nblk = (IMG_W / BX) * (IMG_H / BY) * NIMG;
    const double inv_n = 1.0 / ((double)NIMG * IMG_H * IMG_W);
    ssim_reduce_kernel<<<1, 256, 0, stream>>>(partial, out, nblk, inv_n);
}